// Round 2
// baseline (255.592 us; speedup 1.0000x reference)
//
#include <hip/hip_runtime.h>

#define BB 32
#define CC 3
#define HH 128
#define WW 128
#define NN 1024
#define KK (CC*HH*WW)      // 49152
#define NROWS (CC*HH)      // 384
#define BH 16              // batches per block
#define BSPLIT (BB/BH)     // 2
#define STEP (1.0f/127.0f)

// ---- per-neuron normalization scale: scale[n] = sqrt(H*W/(Sx*Sy)) ----
__global__ void scale_kernel(const float* __restrict__ mu_x,
                             const float* __restrict__ mu_y,
                             const float* __restrict__ sigma_x,
                             const float* __restrict__ sigma_y,
                             float* __restrict__ scale) {
    int n = blockIdx.x * blockDim.x + threadIdx.x;
    if (n >= NN) return;
    float mux = mu_x[n], muy = mu_y[n];
    float isx = 1.0f / sigma_x[n], isy = 1.0f / sigma_y[n];
    float Sx = 0.f, Sy = 0.f;
    for (int i = 0; i < WW; ++i) {
        float dx = (i * STEP - mux) * isx;
        Sx += __expf(-dx * dx);
        float dy = (i * STEP - muy) * isy;
        Sy += __expf(-dy * dy);
    }
    scale[n] = sqrtf((float)(HH * WW) / (Sx * Sy));
}

// ---- gx[w][n] and gy[h][n]*scale[n] tables (HH == WW == 128) ----
__global__ void table_kernel(const float* __restrict__ mu_x,
                             const float* __restrict__ mu_y,
                             const float* __restrict__ sigma_x,
                             const float* __restrict__ sigma_y,
                             const float* __restrict__ scale,
                             float* __restrict__ gxt,
                             float* __restrict__ gyt) {
    int id = blockIdx.x * blockDim.x + threadIdx.x;   // 128*1024 total
    int n = id & (NN - 1);
    int i = id >> 10;
    float sx = sigma_x[n], sy = sigma_y[n];
    float dx = i * STEP - mu_x[n];
    float dy = i * STEP - mu_y[n];
    gxt[id] = __expf(-0.5f * dx * dx / (sx * sx));
    gyt[id] = __expf(-0.5f * dy * dy / (sy * sy)) * scale[n];
}

// ---- main: each block = (one row r, half the batch). lane owns 4 n's. ----
template <bool TBL>
__global__ __launch_bounds__(256, 3) void main_kernel(
    const float* __restrict__ weights,
    const float* __restrict__ x,
    const float* __restrict__ gxt,
    const float* __restrict__ gyt,
    const float* __restrict__ mu_x, const float* __restrict__ mu_y,
    const float* __restrict__ sigma_x, const float* __restrict__ sigma_y,
    float* __restrict__ out)
{
    __shared__ float tile[WW][BH];     // x slice, [w][b], 8 KB
    const int tid = threadIdx.x;
    const int b0  = blockIdx.x * BH;
    const int r   = blockIdx.y;        // 0..383  (r = c*HH + h)
    const int h   = r & (HH - 1);

    // stage x[b0..b0+15][r*WW .. +WW) into LDS transposed
    {
        const int b  = tid & (BH - 1);
        const int kc = tid >> 4;       // 0..15, 8 w's each
        const float* xp = x + (size_t)(b0 + b) * KK + (size_t)r * WW + kc * 8;
        const float4 v0 = ((const float4*)xp)[0];
        const float4 v1 = ((const float4*)xp)[1];
        const int wb = kc * 8;
        tile[wb+0][b] = v0.x; tile[wb+1][b] = v0.y;
        tile[wb+2][b] = v0.z; tile[wb+3][b] = v0.w;
        tile[wb+4][b] = v1.x; tile[wb+5][b] = v1.y;
        tile[wb+6][b] = v1.z; tile[wb+7][b] = v1.w;
    }

    float4 gys, mux4, ax4;
    if constexpr (TBL) {
        gys = ((const float4*)(gyt + (size_t)h * NN))[tid];
    } else {
        // self-contained fallback: compute scale + gys inline
        mux4 = ((const float4*)mu_x)[tid];
        float4 muy4 = ((const float4*)mu_y)[tid];
        float4 sx4  = ((const float4*)sigma_x)[tid];
        float4 sy4  = ((const float4*)sigma_y)[tid];
        ax4.x = -0.5f/(sx4.x*sx4.x); ax4.y = -0.5f/(sx4.y*sx4.y);
        ax4.z = -0.5f/(sx4.z*sx4.z); ax4.w = -0.5f/(sx4.w*sx4.w);
        float4 ay4;
        ay4.x = -0.5f/(sy4.x*sy4.x); ay4.y = -0.5f/(sy4.y*sy4.y);
        ay4.z = -0.5f/(sy4.z*sy4.z); ay4.w = -0.5f/(sy4.w*sy4.w);
        float Sx[4] = {0,0,0,0}, Sy[4] = {0,0,0,0};
        for (int i = 0; i < WW; ++i) {
            float p = i * STEP;
            float d;
            d = p-mux4.x; Sx[0] += __expf(2.f*ax4.x*d*d);
            d = p-mux4.y; Sx[1] += __expf(2.f*ax4.y*d*d);
            d = p-mux4.z; Sx[2] += __expf(2.f*ax4.z*d*d);
            d = p-mux4.w; Sx[3] += __expf(2.f*ax4.w*d*d);
            d = p-muy4.x; Sy[0] += __expf(2.f*ay4.x*d*d);
            d = p-muy4.y; Sy[1] += __expf(2.f*ay4.y*d*d);
            d = p-muy4.z; Sy[2] += __expf(2.f*ay4.z*d*d);
            d = p-muy4.w; Sy[3] += __expf(2.f*ay4.w*d*d);
        }
        float hp = h * STEP;
        float dy0 = hp-muy4.x, dy1 = hp-muy4.y, dy2 = hp-muy4.z, dy3 = hp-muy4.w;
        gys.x = __expf(ay4.x*dy0*dy0) * sqrtf((float)(HH*WW)/(Sx[0]*Sy[0]));
        gys.y = __expf(ay4.y*dy1*dy1) * sqrtf((float)(HH*WW)/(Sx[1]*Sy[1]));
        gys.z = __expf(ay4.z*dy2*dy2) * sqrtf((float)(HH*WW)/(Sx[2]*Sy[2]));
        gys.w = __expf(ay4.w*dy3*dy3) * sqrtf((float)(HH*WW)/(Sx[3]*Sy[3]));
    }
    __syncthreads();

    const float4* wp  = (const float4*)(weights + (size_t)r * WW * NN) + tid;
    const float4* gxp = (const float4*)gxt + tid;

    float acc[BH][4];
#pragma unroll
    for (int b = 0; b < BH; ++b)
        acc[b][0] = acc[b][1] = acc[b][2] = acc[b][3] = 0.f;

    auto GX = [&](int w) -> float4 {
        if constexpr (TBL) {
            return gxp[w * (NN/4)];
        } else {
            float4 g;
            float p = w * STEP, d;
            d = p-mux4.x; g.x = __expf(ax4.x*d*d);
            d = p-mux4.y; g.y = __expf(ax4.y*d*d);
            d = p-mux4.z; g.z = __expf(ax4.z*d*d);
            d = p-mux4.w; g.w = __expf(ax4.w*d*d);
            return g;
        }
    };

#define COMPUTE(WT, GXV, WIDX)                                          \
    {                                                                   \
        float4 t;                                                       \
        t.x = GXV.x * gys.x * WT.x;                                     \
        t.y = GXV.y * gys.y * WT.y;                                     \
        t.z = GXV.z * gys.z * WT.z;                                     \
        t.w = GXV.w * gys.w * WT.w;                                     \
        const float4* tr = (const float4*)&tile[WIDX][0];               \
        float xs[BH];                                                   \
        ((float4*)xs)[0] = tr[0]; ((float4*)xs)[1] = tr[1];             \
        ((float4*)xs)[2] = tr[2]; ((float4*)xs)[3] = tr[3];             \
        _Pragma("unroll")                                               \
        for (int b = 0; b < BH; ++b) {                                  \
            acc[b][0] = fmaf(xs[b], t.x, acc[b][0]);                    \
            acc[b][1] = fmaf(xs[b], t.y, acc[b][1]);                    \
            acc[b][2] = fmaf(xs[b], t.z, acc[b][2]);                    \
            acc[b][3] = fmaf(xs[b], t.w, acc[b][3]);                    \
        }                                                               \
    }

    // 2-deep register pipeline over w-pairs: 4 independent loads in flight
    float4 wtA = wp[0];
    float4 gxA = GX(0);
    float4 wtB = wp[NN/4];
    float4 gxB = GX(1);

    for (int w = 0; w < WW; w += 2) {
        const int wn = (w + 2 < WW) ? (w + 2) : (WW - 2);   // clamp: no OOB
        float4 wtA2 = wp[(size_t)wn * (NN/4)];
        float4 gxA2 = GX(wn);
        float4 wtB2 = wp[(size_t)(wn + 1) * (NN/4)];
        float4 gxB2 = GX(wn + 1);

        COMPUTE(wtA, gxA, w);
        COMPUTE(wtB, gxB, (w + 1));

        wtA = wtA2; gxA = gxA2; wtB = wtB2; gxB = gxB2;
    }
#undef COMPUTE

    float* op = out + (size_t)b0 * NN + tid * 4;
#pragma unroll
    for (int b = 0; b < BH; ++b) {
        atomicAdd(op + (size_t)b * NN + 0, acc[b][0]);
        atomicAdd(op + (size_t)b * NN + 1, acc[b][1]);
        atomicAdd(op + (size_t)b * NN + 2, acc[b][2]);
        atomicAdd(op + (size_t)b * NN + 3, acc[b][3]);
    }
}

extern "C" void kernel_launch(void* const* d_in, const int* in_sizes, int n_in,
                              void* d_out, int out_size, void* d_ws, size_t ws_size,
                              hipStream_t stream) {
    const float* x       = (const float*)d_in[0];
    const float* mu_x    = (const float*)d_in[1];
    const float* mu_y    = (const float*)d_in[2];
    const float* sigma_x = (const float*)d_in[3];
    const float* sigma_y = (const float*)d_in[4];
    const float* weights = (const float*)d_in[5];
    float* out = (float*)d_out;

    float* scale = (float*)d_ws;                          // 4 KB
    float* gxt   = (float*)((char*)d_ws + 4096);          // 512 KB
    float* gyt   = gxt + (size_t)HH * NN;                 // 512 KB
    const size_t need = 4096 + 2 * sizeof(float) * (size_t)HH * NN;

    // out is accumulated atomically -> zero it every call (graph-capture safe)
    hipMemsetAsync(d_out, 0, (size_t)out_size * sizeof(float), stream);

    dim3 grid(BSPLIT, NROWS);   // 2 x 384 = 768 blocks
    if (ws_size >= need) {
        scale_kernel<<<(NN + 255) / 256, 256, 0, stream>>>(mu_x, mu_y, sigma_x, sigma_y, scale);
        table_kernel<<<(HH * NN) / 256, 256, 0, stream>>>(mu_x, mu_y, sigma_x, sigma_y,
                                                          scale, gxt, gyt);
        main_kernel<true><<<grid, 256, 0, stream>>>(weights, x, gxt, gyt,
                                                    mu_x, mu_y, sigma_x, sigma_y, out);
    } else {
        main_kernel<false><<<grid, 256, 0, stream>>>(weights, x, nullptr, nullptr,
                                                     mu_x, mu_y, sigma_x, sigma_y, out);
    }
}

// Round 3
// 96.584 us; speedup vs baseline: 2.6463x; 2.6463x over previous
//
#include <hip/hip_runtime.h>

#define BB 32
#define CC 3
#define HH 128
#define WW 128
#define NN 1024
#define KK (CC*HH*WW)        // 49152
#define NROWS (CC*HH)        // 384
#define RPB 2                // rows per block
#define KSPLIT (NROWS/RPB)   // 192
#define BH 8                 // batches per block
#define BSPLIT (BB/BH)       // 4
#define STEP (1.0f/127.0f)

// ---- per-neuron normalization scale: scale[n] = sqrt(H*W/(Sx*Sy)) ----
__global__ void scale_kernel(const float* __restrict__ mu_x,
                             const float* __restrict__ mu_y,
                             const float* __restrict__ sigma_x,
                             const float* __restrict__ sigma_y,
                             float* __restrict__ scale) {
    int n = blockIdx.x * blockDim.x + threadIdx.x;
    if (n >= NN) return;
    float mux = mu_x[n], muy = mu_y[n];
    float isx = 1.0f / sigma_x[n], isy = 1.0f / sigma_y[n];
    float Sx = 0.f, Sy = 0.f;
    for (int i = 0; i < WW; ++i) {
        float dx = (i * STEP - mux) * isx;
        Sx += __expf(-dx * dx);
        float dy = (i * STEP - muy) * isy;
        Sy += __expf(-dy * dy);
    }
    scale[n] = sqrtf((float)(HH * WW) / (Sx * Sy));
}

// ---- gx[w][n] and gy[h][n]*scale[n] tables ----
__global__ void table_kernel(const float* __restrict__ mu_x,
                             const float* __restrict__ mu_y,
                             const float* __restrict__ sigma_x,
                             const float* __restrict__ sigma_y,
                             const float* __restrict__ scale,
                             float* __restrict__ gxt,
                             float* __restrict__ gyt) {
    int id = blockIdx.x * blockDim.x + threadIdx.x;   // 128*1024
    int n = id & (NN - 1);
    int i = id >> 10;
    float sx = sigma_x[n], sy = sigma_y[n];
    float dx = i * STEP - mu_x[n];
    float dy = i * STEP - mu_y[n];
    gxt[id] = __expf(-0.5f * dx * dx / (sx * sx));
    gyt[id] = __expf(-0.5f * dy * dy / (sy * sy)) * scale[n];
}

// ---- stage 1: block = (row-group g, batch-slice b0). lane owns n=4*tid..+3 ----
// MODE 0: write partials (no atomics).  MODE 1: atomicAdd to out (fallback).
// MODE 2: atomicAdd + inline exp (no-workspace fallback).
template <int MODE>
__global__ __launch_bounds__(256) void main_kernel(
    const float* __restrict__ weights,
    const float* __restrict__ x,
    const float* __restrict__ gxt,
    const float* __restrict__ gyt,
    const float* __restrict__ mu_x, const float* __restrict__ mu_y,
    const float* __restrict__ sigma_x, const float* __restrict__ sigma_y,
    float* __restrict__ dst)    // partials (MODE 0) or out (MODE 1/2)
{
    __shared__ float tile[RPB][WW][BH];   // 8 KB, [row][w][b]
    const int tid = threadIdx.x;
    const int g   = blockIdx.x;           // 0..KSPLIT-1
    const int b0  = blockIdx.y * BH;
    const int r0  = g * RPB;

    // stage x[b0..b0+BH) rows r0..r0+RPB into LDS transposed
    {
        const int b = tid & (BH - 1);
        const int c = tid >> 3;           // 0..31 -> 8 consecutive w-slots
        const float* xp = x + (size_t)(b0 + b) * KK + (size_t)r0 * WW + c * 8;
        const float4 v0 = ((const float4*)xp)[0];
        const float4 v1 = ((const float4*)xp)[1];
        const int row = (c * 8) >> 7;
        const int w   = (c * 8) & (WW - 1);
        tile[row][w+0][b] = v0.x; tile[row][w+1][b] = v0.y;
        tile[row][w+2][b] = v0.z; tile[row][w+3][b] = v0.w;
        tile[row][w+4][b] = v1.x; tile[row][w+5][b] = v1.y;
        tile[row][w+6][b] = v1.z; tile[row][w+7][b] = v1.w;
    }

    // per-lane mask params (MODE 2 only)
    float4 mux4, ax4, ay4, muy4, sc4;
    if constexpr (MODE == 2) {
        mux4 = ((const float4*)mu_x)[tid];
        muy4 = ((const float4*)mu_y)[tid];
        float4 sx4 = ((const float4*)sigma_x)[tid];
        float4 sy4 = ((const float4*)sigma_y)[tid];
        ax4.x=-0.5f/(sx4.x*sx4.x); ax4.y=-0.5f/(sx4.y*sx4.y);
        ax4.z=-0.5f/(sx4.z*sx4.z); ax4.w=-0.5f/(sx4.w*sx4.w);
        ay4.x=-0.5f/(sy4.x*sy4.x); ay4.y=-0.5f/(sy4.y*sy4.y);
        ay4.z=-0.5f/(sy4.z*sy4.z); ay4.w=-0.5f/(sy4.w*sy4.w);
        float Sx[4]={0,0,0,0}, Sy[4]={0,0,0,0};
        for (int i = 0; i < WW; ++i) {
            float p = i * STEP, d;
            d=p-mux4.x; Sx[0]+=__expf(2.f*ax4.x*d*d);
            d=p-mux4.y; Sx[1]+=__expf(2.f*ax4.y*d*d);
            d=p-mux4.z; Sx[2]+=__expf(2.f*ax4.z*d*d);
            d=p-mux4.w; Sx[3]+=__expf(2.f*ax4.w*d*d);
            d=p-muy4.x; Sy[0]+=__expf(2.f*ay4.x*d*d);
            d=p-muy4.y; Sy[1]+=__expf(2.f*ay4.y*d*d);
            d=p-muy4.z; Sy[2]+=__expf(2.f*ay4.z*d*d);
            d=p-muy4.w; Sy[3]+=__expf(2.f*ay4.w*d*d);
        }
        sc4.x = sqrtf((float)(HH*WW)/(Sx[0]*Sy[0]));
        sc4.y = sqrtf((float)(HH*WW)/(Sx[1]*Sy[1]));
        sc4.z = sqrtf((float)(HH*WW)/(Sx[2]*Sy[2]));
        sc4.w = sqrtf((float)(HH*WW)/(Sx[3]*Sy[3]));
    }
    __syncthreads();

    float acc[BH][4];
#pragma unroll
    for (int b = 0; b < BH; ++b)
        acc[b][0] = acc[b][1] = acc[b][2] = acc[b][3] = 0.f;

#pragma unroll
    for (int rr = 0; rr < RPB; ++rr) {
        const int r = r0 + rr;
        const int h = r & (HH - 1);

        float4 gys;
        if constexpr (MODE == 2) {
            float hp = h * STEP, d;
            d=hp-muy4.x; gys.x = __expf(ay4.x*d*d) * sc4.x;
            d=hp-muy4.y; gys.y = __expf(ay4.y*d*d) * sc4.y;
            d=hp-muy4.z; gys.z = __expf(ay4.z*d*d) * sc4.z;
            d=hp-muy4.w; gys.w = __expf(ay4.w*d*d) * sc4.w;
        } else {
            gys = ((const float4*)(gyt + (size_t)h * NN))[tid];
        }

        const float4* wp  = (const float4*)(weights + (size_t)r * WW * NN) + tid;
        const float4* gxp = (const float4*)gxt + tid;

        float racc[BH][4];
#pragma unroll
        for (int b = 0; b < BH; ++b)
            racc[b][0] = racc[b][1] = racc[b][2] = racc[b][3] = 0.f;

        auto GX = [&](int w) -> float4 {
            if constexpr (MODE == 2) {
                float p = w * STEP, d;
                float4 gg;
                d=p-mux4.x; gg.x = __expf(ax4.x*d*d);
                d=p-mux4.y; gg.y = __expf(ax4.y*d*d);
                d=p-mux4.z; gg.z = __expf(ax4.z*d*d);
                d=p-mux4.w; gg.w = __expf(ax4.w*d*d);
                return gg;
            } else {
                return gxp[(size_t)w * (NN/4)];
            }
        };

#define COMPUTE(WIDX, WT, GXV)                                          \
        {                                                               \
            float4 t;                                                   \
            t.x = GXV.x * WT.x; t.y = GXV.y * WT.y;                     \
            t.z = GXV.z * WT.z; t.w = GXV.w * WT.w;                     \
            const float4* tr = (const float4*)&tile[rr][WIDX][0];       \
            float xs[BH];                                               \
            ((float4*)xs)[0] = tr[0]; ((float4*)xs)[1] = tr[1];         \
            _Pragma("unroll")                                           \
            for (int b = 0; b < BH; ++b) {                              \
                racc[b][0] = fmaf(xs[b], t.x, racc[b][0]);              \
                racc[b][1] = fmaf(xs[b], t.y, racc[b][1]);              \
                racc[b][2] = fmaf(xs[b], t.z, racc[b][2]);              \
                racc[b][3] = fmaf(xs[b], t.w, racc[b][3]);              \
            }                                                           \
        }

        // 2-deep register pipeline over w-pairs
        float4 wtA = wp[0];
        float4 gxA = GX(0);
        float4 wtB = wp[NN/4];
        float4 gxB = GX(1);
        for (int w = 0; w < WW; w += 2) {
            const int wn = (w + 2 < WW) ? (w + 2) : (WW - 2);  // clamp, no OOB
            float4 wtA2 = wp[(size_t)wn * (NN/4)];
            float4 gxA2 = GX(wn);
            float4 wtB2 = wp[(size_t)(wn + 1) * (NN/4)];
            float4 gxB2 = GX(wn + 1);
            COMPUTE(w,     wtA, gxA);
            COMPUTE(w + 1, wtB, gxB);
            wtA = wtA2; gxA = gxA2; wtB = wtB2; gxB = gxB2;
        }
#undef COMPUTE

        // fold per-row gy*scale once
#pragma unroll
        for (int b = 0; b < BH; ++b) {
            acc[b][0] = fmaf(gys.x, racc[b][0], acc[b][0]);
            acc[b][1] = fmaf(gys.y, racc[b][1], acc[b][1]);
            acc[b][2] = fmaf(gys.z, racc[b][2], acc[b][2]);
            acc[b][3] = fmaf(gys.w, racc[b][3], acc[b][3]);
        }
    }

    if constexpr (MODE == 0) {
        // plain coalesced float4 stores into this block's private slice
        float* pp = dst + ((size_t)g * BB + b0) * NN + tid * 4;
#pragma unroll
        for (int b = 0; b < BH; ++b)
            *(float4*)(pp + (size_t)b * NN) = *(float4*)&acc[b][0];
    } else {
        float* op = dst + (size_t)b0 * NN + tid * 4;
#pragma unroll
        for (int b = 0; b < BH; ++b) {
            atomicAdd(op + (size_t)b * NN + 0, acc[b][0]);
            atomicAdd(op + (size_t)b * NN + 1, acc[b][1]);
            atomicAdd(op + (size_t)b * NN + 2, acc[b][2]);
            atomicAdd(op + (size_t)b * NN + 3, acc[b][3]);
        }
    }
}

// ---- stage 2: out[cell] = sum_s partials[s][cell] ----
__global__ __launch_bounds__(256) void reduce_kernel(const float* __restrict__ part,
                                                     float* __restrict__ out) {
    const int cell = blockIdx.x * 256 + threadIdx.x;   // 0..BB*NN-1
    float a = 0.f;
#pragma unroll 16
    for (int s = 0; s < KSPLIT; ++s)
        a += part[(size_t)s * (BB * NN) + cell];
    out[cell] = a;
}

extern "C" void kernel_launch(void* const* d_in, const int* in_sizes, int n_in,
                              void* d_out, int out_size, void* d_ws, size_t ws_size,
                              hipStream_t stream) {
    const float* x       = (const float*)d_in[0];
    const float* mu_x    = (const float*)d_in[1];
    const float* mu_y    = (const float*)d_in[2];
    const float* sigma_x = (const float*)d_in[3];
    const float* sigma_y = (const float*)d_in[4];
    const float* weights = (const float*)d_in[5];
    float* out = (float*)d_out;

    float* scale = (float*)d_ws;                          // 4 KB
    float* gxt   = (float*)((char*)d_ws + 4096);          // 512 KB
    float* gyt   = gxt + (size_t)HH * NN;                 // 512 KB
    float* part  = gyt + (size_t)HH * NN;                 // 25.2 MB
    const size_t need_tbl  = 4096 + 2 * sizeof(float) * (size_t)HH * NN;
    const size_t need_part = need_tbl +
        sizeof(float) * (size_t)KSPLIT * BB * NN;

    dim3 grid(KSPLIT, BSPLIT);   // 192 x 4 = 768 blocks

    if (ws_size >= need_part) {
        scale_kernel<<<(NN + 255) / 256, 256, 0, stream>>>(mu_x, mu_y, sigma_x, sigma_y, scale);
        table_kernel<<<(HH * NN) / 256, 256, 0, stream>>>(mu_x, mu_y, sigma_x, sigma_y,
                                                          scale, gxt, gyt);
        main_kernel<0><<<grid, 256, 0, stream>>>(weights, x, gxt, gyt,
                                                 mu_x, mu_y, sigma_x, sigma_y, part);
        reduce_kernel<<<(BB * NN) / 256, 256, 0, stream>>>(part, out);
    } else if (ws_size >= need_tbl) {
        hipMemsetAsync(d_out, 0, (size_t)out_size * sizeof(float), stream);
        scale_kernel<<<(NN + 255) / 256, 256, 0, stream>>>(mu_x, mu_y, sigma_x, sigma_y, scale);
        table_kernel<<<(HH * NN) / 256, 256, 0, stream>>>(mu_x, mu_y, sigma_x, sigma_y,
                                                          scale, gxt, gyt);
        main_kernel<1><<<grid, 256, 0, stream>>>(weights, x, gxt, gyt,
                                                 mu_x, mu_y, sigma_x, sigma_y, out);
    } else {
        hipMemsetAsync(d_out, 0, (size_t)out_size * sizeof(float), stream);
        main_kernel<2><<<grid, 256, 0, stream>>>(weights, x, nullptr, nullptr,
                                                 mu_x, mu_y, sigma_x, sigma_y, out);
    }
}